// Round 16
// baseline (41059.796 us; speedup 1.0000x reference)
//
#include <hip/hip_runtime.h>
#include <stdint.h>
#include <math.h>

typedef unsigned int u32;

constexpr int kB = 512, kS = 128, kH = 512, kE = 256, kT = 100;
constexpr int kNG = 4 * kH; // 2048

// ---- ws layout (f32 elements) ----
constexpr size_t SZ_E = (size_t)kS * kB * kH; // 33,554,432
constexpr size_t OFF_EG  = 0;                              // EG [s][b][h]
constexpr size_t OFF_EP  = OFF_EG + SZ_E;                  // EP [s][b][h]
constexpr size_t OFF_U   = OFF_EP + SZ_E;
constexpr size_t OFF_P   = OFF_U + (size_t)kB * kS;
constexpr size_t OFF_QP  = OFF_P + (size_t)kB * kS;        // kB*kH
constexpr size_t OFF_GL  = OFF_QP + (size_t)kB * kH;       // kB*kH
constexpr size_t OFF_G   = OFF_GL + (size_t)kB * kH;       // kB*kNG
constexpr size_t OFF_HX  = OFF_G + (size_t)kB * kNG;       // kB*kH
constexpr size_t OFF_CX  = OFF_HX + (size_t)kB * kH;       // kB*kH
constexpr size_t OFF_DC  = OFF_CX + (size_t)kB * kH;       // kB*kE
constexpr size_t OFF_FM  = OFF_DC + (size_t)kB * kE;       // kB ints
constexpr size_t OFF_FMM = OFF_FM + kB;
constexpr size_t WS_FLOATS = OFF_FMM + kB;                 // ≈265 MiB (PROVEN available)

// ---------------- sentinel (bail only) ----------------
__global__ __launch_bounds__(256) void sentinel_k(float* __restrict__ outSel, float val) {
  int i = blockIdx.x * blockDim.x + threadIdx.x;
  if (i < kT * kB) outSel[i] = val;
}

// ---------------- threefry2x32 (exact JAX) ----------------
__device__ __forceinline__ u32 rotl32(u32 v, int d) { return (v << d) | (v >> (32 - d)); }

__device__ __forceinline__ void tf2x32(u32 k0, u32 k1, u32 x0, u32 x1, u32& o0, u32& o1) {
  u32 ks2 = k0 ^ k1 ^ 0x1BD11BDAu;
  x0 += k0; x1 += k1;
#define RND_(r) { x0 += x1; x1 = rotl32(x1, r); x1 ^= x0; }
  RND_(13) RND_(15) RND_(26) RND_(6)   x0 += k1;  x1 += ks2 + 1u;
  RND_(17) RND_(29) RND_(16) RND_(24)  x0 += ks2; x1 += k0 + 2u;
  RND_(13) RND_(15) RND_(26) RND_(6)   x0 += k0;  x1 += k1 + 3u;
  RND_(17) RND_(29) RND_(16) RND_(24)  x0 += k1;  x1 += ks2 + 4u;
  RND_(13) RND_(15) RND_(26) RND_(6)   x0 += ks2; x1 += k0 + 5u;
#undef RND_
  o0 = x0; o1 = x1;
}

__device__ __forceinline__ float sigf(float x) { return 1.0f / (1.0f + expf(-x)); }

// ------- E precompute: coalesced W staging; EG/EP original layout -------
__global__ __launch_bounds__(512) void precompute_e(const float* __restrict__ ctx,
                                                    const float* __restrict__ Wg,
                                                    const float* __restrict__ bg,
                                                    const float* __restrict__ Wp,
                                                    const float* __restrict__ bp,
                                                    float* __restrict__ EG,
                                                    float* __restrict__ EP) {
  __shared__ float ctxs[8][512];
  __shared__ float Wgs[512][33];
  __shared__ float Wps[512][33];
  const int tid = threadIdx.x;
  const size_t m0 = (size_t)blockIdx.x * 8;
  for (int idx = tid; idx < 8 * 512; idx += 512) {
    ctxs[idx >> 9][idx & 511] = ctx[(m0 + (idx >> 9)) * 512 + (idx & 511)];
  }
  float accg[8] = {}, accp[8] = {};
  for (int k0 = 0; k0 < 512; k0 += 32) {
    __syncthreads();
    for (int idx = tid; idx < 512 * 32; idx += 512) {
      int row = idx >> 5, kk = idx & 31;
      Wgs[row][kk] = Wg[(size_t)row * 512 + k0 + kk];
      Wps[row][kk] = Wp[(size_t)row * 512 + k0 + kk];
    }
    __syncthreads();
#pragma unroll 4
    for (int kk = 0; kk < 32; ++kk) {
      float wg = Wgs[tid][kk], wp = Wps[tid][kk];
#pragma unroll
      for (int mi = 0; mi < 8; ++mi) {
        float a = ctxs[mi][k0 + kk];
        accg[mi] = fmaf(a, wg, accg[mi]);
        accp[mi] = fmaf(a, wp, accp[mi]);
      }
    }
  }
  float bgv = bg[tid], bpv = bp[tid];
#pragma unroll
  for (int mi = 0; mi < 8; ++mi) {
    size_t m = m0 + mi;
    EG[m * 512 + tid] = accg[mi] + bgv;
    EP[m * 512 + tid] = accp[mi] + bpv;
  }
}

// ------- b-tiled NT GEMM (ascending-k fmaf per output) -------
template <int K, int NB, bool FIRST>
__global__ __launch_bounds__(512) void gemm_v2(const float* __restrict__ A,
                                               const float* __restrict__ W,
                                               const float* __restrict__ bias,
                                               const float* __restrict__ Cin,
                                               float* __restrict__ C, int N) {
  __shared__ float As[NB][K];
  __shared__ float Ws[512][33];
  const int b0 = blockIdx.y * NB;
  const int o0 = blockIdx.x * 512;
  const int tid = threadIdx.x;
  for (int idx = tid; idx < NB * K; idx += 512) {
    int bb = idx / K, k = idx % K;
    As[bb][k] = A[(size_t)(b0 + bb) * K + k];
  }
  float acc[NB] = {};
  for (int k0 = 0; k0 < K; k0 += 32) {
    __syncthreads();
    for (int idx = tid; idx < 512 * 32; idx += 512) {
      int row = idx >> 5, kk = idx & 31;
      Ws[row][kk] = W[(size_t)(o0 + row) * K + k0 + kk];
    }
    __syncthreads();
#pragma unroll 4
    for (int kk = 0; kk < 32; ++kk) {
      float w = Ws[tid][kk];
#pragma unroll
      for (int bb = 0; bb < NB; ++bb) acc[bb] = fmaf(As[bb][k0 + kk], w, acc[bb]);
    }
  }
  float bv = bias[o0 + tid];
#pragma unroll
  for (int bb = 0; bb < NB; ++bb) {
    size_t off = (size_t)(b0 + bb) * N + o0 + tid;
    C[off] = FIRST ? (acc[bb] + bv) : ((Cin[off] + acc[bb]) + bv);
  }
}

// ---------------- init state ----------------
__global__ __launch_bounds__(256) void init_k(const float* __restrict__ dec_in,
                                              const float* __restrict__ hx0,
                                              const float* __restrict__ cx0,
                                              float* __restrict__ dec, float* __restrict__ hx,
                                              float* __restrict__ cx, int* __restrict__ fm,
                                              int* __restrict__ fmm) {
  int i = blockIdx.x * blockDim.x + threadIdx.x;
  if (i < kB * kH) { hx[i] = hx0[i]; cx[i] = cx0[i]; }
  if (i < kB * kE) dec[i] = dec_in[i];
  if (i < kB) { fm[i] = 1; fmm[i] = 1; }
}

// ---------------- LSTM elementwise ----------------
__global__ __launch_bounds__(256) void lstm_act(const float* __restrict__ gates,
                                                float* __restrict__ hx, float* __restrict__ cx) {
  int i = blockIdx.x * blockDim.x + threadIdx.x;
  int b = i >> 9, h = i & (kH - 1);
  const float* g = gates + (size_t)b * kNG;
  float ig = g[h], fg = g[h + kH], cg = g[h + 2 * kH], og = g[h + 3 * kH];
  float cyv = sigf(fg) * cx[i] + sigf(ig) * tanhf(cg);
  float hyv = sigf(og) * tanhf(cyv);
  cx[i] = cyv;
  hx[i] = hyv;
}

// ======= fused_A: att1-u + softmax + gl (per-b, lightweight LDS) =======
__global__ __launch_bounds__(512) void fused_A(const float* __restrict__ EG,
                                               const float* __restrict__ qp,
                                               const float* __restrict__ gv,
                                               float* __restrict__ GL) {
  __shared__ float qs[512], gvs[512], gls_unused[1];
  __shared__ float u[128], ps[128];
  __shared__ float mred, sred;
  const int b = blockIdx.x;
  const int tid = threadIdx.x;
  const int wave = tid >> 6, lane = tid & 63;

  qs[tid] = qp[(size_t)b * kH + tid];
  gvs[tid] = gv[tid];
  __syncthreads();

  // att1 u[s]: wave-per-s, lanes split h (stride 64), shuffle reduce (R15 order)
  for (int r = 0; r < 16; ++r) {
    int s = wave + 8 * r;
    const float* row = EG + ((size_t)s * kB + b) * kH;
    float a = 0.f;
#pragma unroll
    for (int i = 0; i < 8; ++i) {
      int h = lane + 64 * i;
      a = fmaf(gvs[h], tanhf(qs[h] + row[h]), a);
    }
#pragma unroll
    for (int off = 32; off > 0; off >>= 1) a += __shfl_xor(a, off);
    if (lane == 0) u[s] = a;
  }
  __syncthreads();

  // softmax over s (serial max/sum semantics, proven)
  if (tid == 0) { float m = u[0]; for (int i = 1; i < 128; ++i) m = fmaxf(m, u[i]); mred = m; }
  __syncthreads();
  if (tid < 128) ps[tid] = expf(u[tid] - mred);
  __syncthreads();
  if (tid == 0) { float s = 0.f; for (int i = 0; i < 128; ++i) s += ps[i]; sred = s; }
  __syncthreads();
  if (tid < 128) ps[tid] = ps[tid] / sred;
  __syncthreads();

  // gl[h] = serial_s fmaf(EG[s][b][h], P[s]) (R13/R15 order)
  float acc = 0.f;
  for (int s = 0; s < 128; ++s) acc = fmaf(EG[((size_t)s * kB + b) * kH + tid], ps[s], acc);
  GL[(size_t)b * kH + tid] = acc;
  (void)gls_unused;
}

// ======= fused_B: att2-u + logits + gumbel + argmax + masks + gather =======
__global__ __launch_bounds__(512) void fused_B(const float* __restrict__ EP,
                                               const float* __restrict__ qp,
                                               const float* __restrict__ pv,
                                               const float* __restrict__ emb,
                                               const int* __restrict__ counts,
                                               float* __restrict__ DC, int* __restrict__ fmask,
                                               int* __restrict__ fmmask, float* __restrict__ outP,
                                               float* __restrict__ outSel, int t) {
  __shared__ float qs[512], gvs[512];
  __shared__ float u[128], sL[128], ex[128], kv[128];
  __shared__ float mred, sred, sMult;
  __shared__ int sIdx;
  const int b = blockIdx.x;
  const int tid = threadIdx.x;
  const int wave = tid >> 6, lane = tid & 63;

  qs[tid] = qp[(size_t)b * kH + tid];
  gvs[tid] = pv[tid];
  __syncthreads();

  for (int r = 0; r < 16; ++r) {
    int s = wave + 8 * r;
    const float* row = EP + ((size_t)s * kB + b) * kH;
    float a = 0.f;
#pragma unroll
    for (int i = 0; i < 8; ++i) {
      int h = lane + 64 * i;
      a = fmaf(gvs[h], tanhf(qs[h] + row[h]), a);
    }
#pragma unroll
    for (int off = 32; off > 0; off >>= 1) a += __shfl_xor(a, off);
    if (lane == 0) u[s] = a;
  }
  __syncthreads();

  if (tid < 128) sL[tid] = 10.0f * tanhf(u[tid]);
  __syncthreads();
  if (tid == 0) { float m = sL[0]; for (int i = 1; i < 128; ++i) m = fmaxf(m, sL[i]); mred = m; }
  __syncthreads();
  if (tid < 128) ex[tid] = expf(sL[tid] - mred);
  __syncthreads();
  if (tid == 0) { float s = 0.f; for (int i = 0; i < 128; ++i) s += ex[i]; sred = s; }
  __syncthreads();
  if (tid < 128) {
    u32 fk0, fk1;
    tf2x32(0u, 42u, 0u, (u32)t, fk0, fk1);
    // partitionable 32-bit path: counter (0, j); bits = out0 ^ out1
    u32 j = (u32)(b * kS + tid);
    u32 y0, y1;
    tf2x32(fk0, fk1, 0u, j, y0, y1);
    u32 bits = y0 ^ y1;
    float f = __uint_as_float(0x3f800000u | (bits >> 9)) - 1.0f;
    float uu = (f > 0.0f) ? f : 1.17549435082228751e-38f;
    float z = -logf(-logf(uu));
    kv[tid] = sL[tid] + z;
  }
  __syncthreads();
  if (tid == 0) {
    float best = kv[0];
    int ia = 0;
    for (int i = 1; i < 128; ++i)
      if (kv[i] > best) { best = kv[i]; ia = i; } // first-index tie-break
    int fm = fmask[b], fmm = fmmask[b];
    int idx = ia * fm;
    outSel[(size_t)t * kB + b] = (float)idx;
    fmask[b] = (idx != 0) ? fm : 0;
    fmmask[b] = (t == counts[b]) ? 0 : fmm;
    sIdx = idx;
    sMult = (float)(fm * fmm);
  }
  __syncthreads();
  if (tid < 128) outP[((size_t)b * kT + t) * kS + tid] = (ex[tid] / sred) * sMult;
  if (tid < 256) DC[(size_t)b * kE + tid] = emb[((size_t)sIdx * kB + b) * kE + tid];
}

// ---------------- final hx/cx copy ----------------
__global__ __launch_bounds__(256) void final_copy(const float* __restrict__ hx,
                                                  const float* __restrict__ cx,
                                                  float* __restrict__ o2, float* __restrict__ o3) {
  int i = blockIdx.x * blockDim.x + threadIdx.x;
  if (i < kB * kH) { o2[i] = hx[i]; o3[i] = cx[i]; }
}

extern "C" void kernel_launch(void* const* d_in, const int* in_sizes, int n_in, void* d_out,
                              int out_size, void* d_ws, size_t ws_size, hipStream_t stream) {
  const float* dec_in = (const float*)d_in[0];
  const float* emb = (const float*)d_in[1];
  const float* hx0 = (const float*)d_in[2];
  const float* cx0 = (const float*)d_in[3];
  const float* ctx = (const float*)d_in[4];
  const int* counts = (const int*)d_in[5];
  const float* Wi = (const float*)d_in[7];
  const float* bi = (const float*)d_in[8];
  const float* Wh = (const float*)d_in[9];
  const float* bh = (const float*)d_in[10];
  const float* gWq = (const float*)d_in[11];
  const float* gbq = (const float*)d_in[12];
  const float* gWr = (const float*)d_in[13];
  const float* gbr = (const float*)d_in[14];
  const float* gv = (const float*)d_in[15];
  const float* pWq = (const float*)d_in[16];
  const float* pbq = (const float*)d_in[17];
  const float* pWr = (const float*)d_in[18];
  const float* pbr = (const float*)d_in[19];
  const float* pv = (const float*)d_in[20];

  float* out = (float*)d_out;
  float* outP = out;                          // (B*T, S)
  float* outSel = out + (size_t)kB * kT * kS; // (T, B)
  float* outHx = outSel + (size_t)kT * kB;    // (B, H)
  float* outCx = outHx + (size_t)kB * kH;     // (B, H)

  if (ws_size < WS_FLOATS * sizeof(float)) {
    double wsMB = (double)ws_size / (1024.0 * 1024.0);
    if (wsMB > 80000.0) wsMB = 80000.0;
    hipLaunchKernelGGL(sentinel_k, dim3((kT * kB + 255) / 256), dim3(256), 0, stream, outSel,
                       (float)(1000.0 + wsMB));
    return;
  }

  float* base = (float*)d_ws;
  float* EG = base + OFF_EG;
  float* EP = base + OFF_EP;
  float* QP = base + OFF_QP;
  float* GL = base + OFF_GL;
  float* G  = base + OFF_G;
  float* HX = base + OFF_HX;
  float* CX = base + OFF_CX;
  float* DC = base + OFF_DC;
  int* FM  = (int*)(base + OFF_FM);
  int* FMM = (int*)(base + OFF_FMM);

  hipLaunchKernelGGL(precompute_e, dim3(kS * kB / 8), dim3(512), 0, stream, ctx, gWr, gbr, pWr,
                     pbr, EG, EP);
  hipLaunchKernelGGL(init_k, dim3(kB * kH / 256), dim3(256), 0, stream, dec_in, hx0, cx0, DC, HX,
                     CX, FM, FMM);

  for (int t = 0; t < kT; ++t) {
    hipLaunchKernelGGL((gemm_v2<256, 8, true>), dim3(4, 64), dim3(512), 0, stream, DC, Wi, bi,
                       (const float*)nullptr, G, kNG);
    hipLaunchKernelGGL((gemm_v2<512, 8, false>), dim3(4, 64), dim3(512), 0, stream, HX, Wh, bh, G,
                       G, kNG);
    hipLaunchKernelGGL(lstm_act, dim3(kB * kH / 256), dim3(256), 0, stream, G, HX, CX);
    hipLaunchKernelGGL((gemm_v2<512, 4, true>), dim3(1, 128), dim3(512), 0, stream, HX, gWq, gbq,
                       (const float*)nullptr, QP, kH);
    hipLaunchKernelGGL(fused_A, dim3(kB), dim3(512), 0, stream, EG, QP, gv, GL);
    hipLaunchKernelGGL((gemm_v2<512, 4, true>), dim3(1, 128), dim3(512), 0, stream, GL, pWq, pbq,
                       (const float*)nullptr, QP, kH);
    hipLaunchKernelGGL(fused_B, dim3(kB), dim3(512), 0, stream, EP, QP, pv, emb, counts, DC, FM,
                       FMM, outP, outSel, t);
  }
  hipLaunchKernelGGL(final_copy, dim3(kB * kH / 256), dim3(256), 0, stream, HX, CX, outHx, outCx);
}